// Round 1
// baseline (11995.479 us; speedup 1.0000x reference)
//
#include <hip/hip_runtime.h>
#include <math.h>

// Problem constants
#define BZ   32
#define TENC 1500
#define DD   512      // E == H == A == ATT_H == 512
#define VV   10000
#define LL   100
#define SS   101      // L+1 steps
#define G4   2048     // 4*H
#define KCZ  1024     // H + A

// d_out float offsets
#define OUT_LOGITS 0
#define OUT_ENCP   0                      // scratch overlay (dead before logits written)
#define OUT_PREG   24576000               // 32*1500*512
#define OUT_YSLP   32320000               // 32*101*10000
#define OUT_PRED   32323232
#define OUT_WS     32326464

__device__ inline float sigm(float x) { return 1.f / (1.f + __expf(-x)); }
__device__ inline float tanh_fast(float x) {
    x = fminf(15.f, fmaxf(-15.f, x));
    float e = __expf(2.f * x);
    return (e - 1.f) / (e + 1.f);
}

// ---------------------------------------------------------------------------
// Zero init: za slot 0 (32x1024) + c_state (32x512)
__global__ void zero_kernel(float* za0, float* cs) {
    int i = blockIdx.x * 256 + threadIdx.x;
    if (i < 32768) za0[i] = 0.f;
    else cs[i - 32768] = 0.f;
}

// ---------------------------------------------------------------------------
// Tiled fp32 GEMM, 128x128 tile, 8x8 per thread.
// MODE 0: enc_proj = enc_pad[48000x512] @ W_enc[512x512]         (B normal)
// MODE 1: pre_g = emb[tok][3232x512] @ W_ih[:, :512]^T + biases  (B transposed, A gathered)
// MODE 2: logits = za(+32 rows)[3232x1024] @ W_out^T + b_out     (B transposed, scattered out rows)
template<int MODE>
__global__ __launch_bounds__(256) void gemm_tile(
    const float* __restrict__ Abase, const float* __restrict__ Bmat,
    const float* __restrict__ bias0, const float* __restrict__ bias1,
    const int* __restrict__ ys, float* __restrict__ Out,
    int M, int N, int K)
{
    __shared__ float As[16][132];
    __shared__ float Bs[16][132];
    const int tid = threadIdx.x;
    const int row0 = blockIdx.y * 128, n0 = blockIdx.x * 128;

    // A loader mapping: 2x float4 per thread
    const int ar = tid >> 1, ah = tid & 1;
    int am = row0 + ar; if (am > M - 1) am = M - 1;
    const float* Arow;
    if (MODE == 0) {
        Arow = Abase + (size_t)am * 512;
    } else if (MODE == 1) {
        int t = am >> 5, b = am & 31;
        int tok = (t == 0) ? 1 : ys[b * LL + t - 1];
        Arow = Abase + (size_t)tok * 512;
    } else {
        Arow = Abase + (size_t)(am + 32) * 1024;
    }
    // B loader mapping
    const int bk = tid >> 4, bg = tid & 15;          // MODE 0
    const int bn = tid >> 1, bh = tid & 1;           // MODE 1/2
    int bnn = n0 + bn; if (bnn > N - 1) bnn = N - 1;

    const int tx = tid & 15, ty = tid >> 4;
    const int rr = ty * 8, cc = tx * 8;
    float acc[8][8] = {{0.f}};

    for (int k0 = 0; k0 < K; k0 += 16) {
        float4 a0 = *(const float4*)(Arow + k0 + ah * 8);
        float4 a1 = *(const float4*)(Arow + k0 + ah * 8 + 4);
        As[ah*8+0][ar] = a0.x; As[ah*8+1][ar] = a0.y; As[ah*8+2][ar] = a0.z; As[ah*8+3][ar] = a0.w;
        As[ah*8+4][ar] = a1.x; As[ah*8+5][ar] = a1.y; As[ah*8+6][ar] = a1.z; As[ah*8+7][ar] = a1.w;
        if (MODE == 0) {
            const float* bp = Bmat + (size_t)(k0 + bk) * N + n0 + bg * 8;
            float4 b0 = *(const float4*)(bp);
            float4 b1 = *(const float4*)(bp + 4);
            *(float4*)&Bs[bk][bg * 8]     = b0;
            *(float4*)&Bs[bk][bg * 8 + 4] = b1;
        } else {
            const float* bp = Bmat + (size_t)bnn * 1024 + k0 + bh * 8;
            float4 b0 = *(const float4*)(bp);
            float4 b1 = *(const float4*)(bp + 4);
            Bs[bh*8+0][bn] = b0.x; Bs[bh*8+1][bn] = b0.y; Bs[bh*8+2][bn] = b0.z; Bs[bh*8+3][bn] = b0.w;
            Bs[bh*8+4][bn] = b1.x; Bs[bh*8+5][bn] = b1.y; Bs[bh*8+6][bn] = b1.z; Bs[bh*8+7][bn] = b1.w;
        }
        __syncthreads();
        #pragma unroll
        for (int kk = 0; kk < 16; ++kk) {
            float4 A0 = *(const float4*)&As[kk][rr];
            float4 A1 = *(const float4*)&As[kk][rr + 4];
            float4 B0 = *(const float4*)&Bs[kk][cc];
            float4 B1 = *(const float4*)&Bs[kk][cc + 4];
            float av[8] = {A0.x, A0.y, A0.z, A0.w, A1.x, A1.y, A1.z, A1.w};
            float bv[8] = {B0.x, B0.y, B0.z, B0.w, B1.x, B1.y, B1.z, B1.w};
            #pragma unroll
            for (int i = 0; i < 8; ++i)
                #pragma unroll
                for (int j = 0; j < 8; ++j)
                    acc[i][j] += av[i] * bv[j];
        }
        __syncthreads();
    }
    // epilogue
    #pragma unroll
    for (int i = 0; i < 8; ++i) {
        int m = row0 + rr + i;
        if (m >= M) continue;
        size_t orow;
        if (MODE == 2) { int t = m >> 5, b = m & 31; orow = ((size_t)b * SS + t) * (size_t)N; }
        else orow = (size_t)m * N;
        #pragma unroll
        for (int j = 0; j < 8; ++j) {
            int n = n0 + cc + j;
            if (n < N) {
                float v = acc[i][j];
                if (MODE == 1) v += bias0[n] + bias1[n];
                if (MODE == 2) v += bias0[n];
                Out[orow + n] = v;
            }
        }
    }
}

// ---------------------------------------------------------------------------
// Per-step gates: gates[b][r] = pre_g[t][b][r] + z.W_hh[r] + c.W_ih[r,512:]
__global__ __launch_bounds__(256) void k_gates(
    const float* __restrict__ za_t, const float* __restrict__ pre_g_t,
    const float* __restrict__ W_ih, const float* __restrict__ W_hh,
    float* __restrict__ gates)
{
    const int tid = threadIdx.x;
    const int b = tid & 31, rl = tid >> 5;
    const int r = blockIdx.x * 8 + rl;
    const float* zrow = za_t + b * KCZ;          // [z(512) | c(512)]
    const float* wh = W_hh + (size_t)r * 512;
    const float* wi = W_ih + (size_t)r * 1024 + 512;
    float acc = 0.f;
    #pragma unroll 4
    for (int k = 0; k < 512; k += 4) {
        float4 z4 = *(const float4*)(zrow + k);
        float4 w4 = *(const float4*)(wh + k);
        acc += z4.x * w4.x + z4.y * w4.y + z4.z * w4.z + z4.w * w4.w;
    }
    const float* crow = zrow + 512;
    #pragma unroll 4
    for (int k = 0; k < 512; k += 4) {
        float4 c4 = *(const float4*)(crow + k);
        float4 w4 = *(const float4*)(wi + k);
        acc += c4.x * w4.x + c4.y * w4.y + c4.z * w4.z + c4.w * w4.w;
    }
    gates[b * G4 + r] = acc + pre_g_t[b * G4 + r];
}

// ---------------------------------------------------------------------------
// LSTM elementwise; also zeroes this step's attention accumulators
__global__ void k_lstm(const float* __restrict__ gates, float* __restrict__ c_state,
                       float* __restrict__ za_next, float* __restrict__ c_un,
                       float* __restrict__ l_b)
{
    const int b = blockIdx.x, tid = threadIdx.x;
    const float* g = gates + b * G4;
    for (int h = tid; h < 512; h += 256) {
        float ig = sigm(g[h]);
        float fg = sigm(g[512 + h]);
        float gg = tanhf(g[1024 + h]);
        float og = sigm(g[1536 + h]);
        float c = fg * c_state[b * 512 + h] + ig * gg;
        c_state[b * 512 + h] = c;
        za_next[b * KCZ + h] = og * tanhf(c);
    }
    for (int d = tid; d < 512; d += 256) c_un[b * 512 + d] = 0.f;
    if (tid == 0) l_b[b] = 0.f;
}

// ---------------------------------------------------------------------------
// q = z @ W_dec. grid (16 jc, 4 bq), thread: j = jc*32 + lane32, b = bq*8 + tid/32
__global__ __launch_bounds__(256) void k_qproj(const float* __restrict__ za_next,
                                               const float* __restrict__ W_dec,
                                               float* __restrict__ q)
{
    const int tid = threadIdx.x;
    const int j = blockIdx.x * 32 + (tid & 31);
    const int b = blockIdx.y * 8 + (tid >> 5);
    const float* z = za_next + b * KCZ;
    float acc = 0.f;
    #pragma unroll 4
    for (int h = 0; h < 512; h += 4) {
        float4 z4 = *(const float4*)(z + h);
        acc += z4.x * W_dec[(h + 0) * 512 + j];
        acc += z4.y * W_dec[(h + 1) * 512 + j];
        acc += z4.z * W_dec[(h + 2) * 512 + j];
        acc += z4.w * W_dec[(h + 3) * 512 + j];
    }
    q[b * 512 + j] = acc;
}

// ---------------------------------------------------------------------------
// Fused attention: e -> p=exp(e-10) -> unnormalized context, one read pass.
// grid (12 t-chunks, 32 b), 256 threads = 4 waves; wave handles one t' at a time.
__global__ __launch_bounds__(256) void k_att(
    const float* __restrict__ enc_proj, const float* __restrict__ enc_pad,
    const float* __restrict__ q, const float* __restrict__ v_att,
    const int* __restrict__ enc_len,
    float* __restrict__ p_buf, float* __restrict__ c_un, float* __restrict__ l_b)
{
    __shared__ float q_s[512], v_s[512];
    __shared__ float accs[4][512];
    __shared__ float lsum_s[4];
    const int b = blockIdx.y, tc = blockIdx.x, tid = threadIdx.x;
    for (int i = tid; i < 512; i += 256) { q_s[i] = q[b * 512 + i]; v_s[i] = v_att[i]; }
    __syncthreads();
    const int len = enc_len[b];
    const int base = tc * 128;
    int tlim = base + 128;
    if (tlim > TENC) tlim = TENC;
    if (tlim > len) tlim = len;
    const int wave = tid >> 6, lane = tid & 63;
    float a[8] = {0.f, 0.f, 0.f, 0.f, 0.f, 0.f, 0.f, 0.f};
    float lacc = 0.f;
    float qv[8], vv[8];
    #pragma unroll
    for (int j = 0; j < 8; ++j) { qv[j] = q_s[lane * 8 + j]; vv[j] = v_s[lane * 8 + j]; }

    for (int tp = base + wave; tp < tlim; tp += 4) {
        const float* ep = enc_proj + ((size_t)b * TENC + tp) * 512 + lane * 8;
        float4 e0 = *(const float4*)(ep);
        float4 e1 = *(const float4*)(ep + 4);
        float s = tanh_fast(e0.x + qv[0]) * vv[0] + tanh_fast(e0.y + qv[1]) * vv[1]
                + tanh_fast(e0.z + qv[2]) * vv[2] + tanh_fast(e0.w + qv[3]) * vv[3]
                + tanh_fast(e1.x + qv[4]) * vv[4] + tanh_fast(e1.y + qv[5]) * vv[5]
                + tanh_fast(e1.z + qv[6]) * vv[6] + tanh_fast(e1.w + qv[7]) * vv[7];
        #pragma unroll
        for (int off = 32; off > 0; off >>= 1) s += __shfl_xor(s, off);
        float p = __expf(s - 10.f);
        if (lane == 0) p_buf[b * TENC + tp] = p;
        lacc += p;
        const float* xp = enc_pad + ((size_t)b * TENC + tp) * 512 + lane * 8;
        float4 x0 = *(const float4*)(xp);
        float4 x1 = *(const float4*)(xp + 4);
        a[0] += p * x0.x; a[1] += p * x0.y; a[2] += p * x0.z; a[3] += p * x0.w;
        a[4] += p * x1.x; a[5] += p * x1.y; a[6] += p * x1.z; a[7] += p * x1.w;
    }
    #pragma unroll
    for (int j = 0; j < 8; ++j) accs[wave][lane * 8 + j] = a[j];
    if (lane == 0) lsum_s[wave] = lacc;
    __syncthreads();
    for (int d = tid; d < 512; d += 256) {
        float s = accs[0][d] + accs[1][d] + accs[2][d] + accs[3][d];
        atomicAdd(&c_un[b * 512 + d], s);
    }
    if (tid == 0) atomicAdd(&l_b[b], lsum_s[0] + lsum_s[1] + lsum_s[2] + lsum_s[3]);
}

// ---------------------------------------------------------------------------
// Finalize step: c = c_un/l into za_next, write normalized w (zeros beyond enc_len)
__global__ void k_fin(const float* __restrict__ p_buf, const float* __restrict__ c_un,
                      const float* __restrict__ l_b, const int* __restrict__ enc_len,
                      float* __restrict__ za_next, float* __restrict__ w_out)
{
    const int b = blockIdx.x, tid = threadIdx.x;
    const float linv = 1.f / l_b[b];
    for (int d = tid; d < 512; d += 256)
        za_next[b * KCZ + 512 + d] = c_un[b * 512 + d] * linv;
    const int len = enc_len[b];
    float* wrow = w_out + (size_t)b * (SS * TENC);
    for (int tp = tid; tp < TENC; tp += 256)
        wrow[tp] = (tp < len) ? p_buf[b * TENC + tp] * linv : 0.f;
}

// ---------------------------------------------------------------------------
// Per-row log-softmax stats: max, argmax(first), logsumexp -> ys_lp, pred
__global__ __launch_bounds__(256) void k_logsm(const float* __restrict__ logits,
                                               const int* __restrict__ ys,
                                               float* __restrict__ ys_lp,
                                               float* __restrict__ pred)
{
    __shared__ float sval[256];
    __shared__ int   sidx[256];
    __shared__ float ssum[256];
    const int bid = blockIdx.x, tid = threadIdx.x;
    const float* row = logits + (size_t)bid * VV;
    float vmax = -3.4e38f; int imax = 0;
    for (int v4 = tid; v4 < VV / 4; v4 += 256) {
        float4 x = *(const float4*)(row + v4 * 4);
        int basei = v4 * 4;
        if (x.x > vmax) { vmax = x.x; imax = basei; }
        if (x.y > vmax) { vmax = x.y; imax = basei + 1; }
        if (x.z > vmax) { vmax = x.z; imax = basei + 2; }
        if (x.w > vmax) { vmax = x.w; imax = basei + 3; }
    }
    sval[tid] = vmax; sidx[tid] = imax;
    __syncthreads();
    for (int s = 128; s > 0; s >>= 1) {
        if (tid < s) {
            float v2 = sval[tid + s]; int i2 = sidx[tid + s];
            if (v2 > sval[tid] || (v2 == sval[tid] && i2 < sidx[tid])) { sval[tid] = v2; sidx[tid] = i2; }
        }
        __syncthreads();
    }
    const float gmax = sval[0];
    float lsum = 0.f;
    for (int v4 = tid; v4 < VV / 4; v4 += 256) {
        float4 x = *(const float4*)(row + v4 * 4);
        lsum += __expf(x.x - gmax) + __expf(x.y - gmax) + __expf(x.z - gmax) + __expf(x.w - gmax);
    }
    ssum[tid] = lsum;
    __syncthreads();
    for (int s = 128; s > 0; s >>= 1) {
        if (tid < s) ssum[tid] += ssum[tid + s];
        __syncthreads();
    }
    if (tid == 0) {
        int b = bid / SS, t = bid % SS;
        int tok = (t < LL) ? ys[b * LL + t] : 2;   // EOS = 2
        ys_lp[bid] = row[tok] - gmax - logf(ssum[0]);
        pred[bid]  = (float)sidx[0];
    }
}

// ---------------------------------------------------------------------------
extern "C" void kernel_launch(void* const* d_in, const int* in_sizes, int n_in,
                              void* d_out, int out_size, void* d_ws, size_t ws_size,
                              hipStream_t stream)
{
    const float* enc_pad = (const float*)d_in[0];
    const int*   enc_len = (const int*)d_in[1];
    const int*   ys      = (const int*)d_in[2];
    const float* emb     = (const float*)d_in[3];
    const float* W_ih    = (const float*)d_in[4];
    const float* W_hh    = (const float*)d_in[5];
    const float* b_ih    = (const float*)d_in[6];
    const float* b_hh    = (const float*)d_in[7];
    const float* W_enc   = (const float*)d_in[8];
    const float* W_dec   = (const float*)d_in[9];
    const float* v_att   = (const float*)d_in[10];
    const float* W_out   = (const float*)d_in[11];
    const float* b_out   = (const float*)d_in[12];

    float* out = (float*)d_out;
    float* enc_proj = out + OUT_ENCP;
    float* pre_g    = out + OUT_PREG;
    float* logits   = out + OUT_LOGITS;
    float* ys_lp    = out + OUT_YSLP;
    float* predo    = out + OUT_PRED;
    float* wsatt    = out + OUT_WS;

    float* ws = (float*)d_ws;
    float* za      = ws;                    // 102*32*1024 = 3342336
    float* c_state = za + 3342336;          // 16384
    float* gates   = c_state + 16384;       // 65536
    float* q       = gates + 65536;         // 16384
    float* p_buf   = q + 16384;             // 48000
    float* l_b     = p_buf + 48000;         // 32
    float* c_un    = l_b + 32;              // 16384

    // Prologue
    zero_kernel<<<192, 256, 0, stream>>>(za, c_state);
    gemm_tile<0><<<dim3(4, 375), 256, 0, stream>>>(enc_pad, W_enc, nullptr, nullptr, nullptr,
                                                   enc_proj, BZ * TENC, 512, 512);
    gemm_tile<1><<<dim3(16, 26), 256, 0, stream>>>(emb, W_ih, b_ih, b_hh, ys,
                                                   pre_g, BZ * SS, G4, 512);

    // Sequential decode
    for (int t = 0; t < SS; ++t) {
        float* za_t    = za + (size_t)t * (BZ * KCZ);
        float* za_next = za + (size_t)(t + 1) * (BZ * KCZ);
        k_gates<<<256, 256, 0, stream>>>(za_t, pre_g + (size_t)t * (BZ * G4), W_ih, W_hh, gates);
        k_lstm<<<32, 256, 0, stream>>>(gates, c_state, za_next, c_un, l_b);
        k_qproj<<<dim3(16, 4), 256, 0, stream>>>(za_next, W_dec, q);
        k_att<<<dim3(12, 32), 256, 0, stream>>>(enc_proj, enc_pad, q, v_att, enc_len,
                                                p_buf, c_un, l_b);
        k_fin<<<32, 256, 0, stream>>>(p_buf, c_un, l_b, enc_len, za_next,
                                      wsatt + (size_t)t * TENC);
    }

    // Epilogue
    gemm_tile<2><<<dim3(79, 26), 256, 0, stream>>>(za, W_out, b_out, nullptr, nullptr,
                                                   logits, BZ * SS, VV, 1024);
    k_logsm<<<BZ * SS, 256, 0, stream>>>(logits, ys, ys_lp, predo);
}